// Round 3
// 184.820 us; speedup vs baseline: 1.0048x; 1.0048x over previous
//
#include <hip/hip_runtime.h>

#define CNT   2048
#define TPB   256
#define CHUNK 8          // 256 * 8 = 2048 >= CNT-1 steps
#define NWAVE (TPB / 64)

struct Q { float w, x, y, z; };

// full quaternion product: 16 fma-class ops, 3-deep chains
__device__ __forceinline__ Q qmul(const Q a, const Q b) {
    Q o;
    o.w = fmaf(a.w, b.w, fmaf(-a.x, b.x, fmaf(-a.y, b.y, -a.z * b.z)));
    o.x = fmaf(a.w, b.x, fmaf( a.x, b.w, fmaf( a.y, b.z, -a.z * b.y)));
    o.y = fmaf(a.w, b.y, fmaf(-a.x, b.z, fmaf( a.y, b.w,  a.z * b.x)));
    o.z = fmaf(a.w, b.z, fmaf( a.x, b.y, fmaf(-a.y, b.x,  a.z * b.w)));
    return o;
}

// qmul specialized for b.w == 1: 12 fma, 3-deep chains
__device__ __forceinline__ Q qmul1(const Q a, const float bx, const float by, const float bz) {
    Q o;
    o.w = fmaf(-a.x, bx, fmaf(-a.y, by, fmaf(-a.z, bz, a.w)));
    o.x = fmaf( a.w, bx, fmaf( a.y, bz, fmaf(-a.z, by, a.x)));
    o.y = fmaf( a.w, by, fmaf(-a.x, bz, fmaf( a.z, bx, a.y)));
    o.z = fmaf( a.w, bz, fmaf( a.x, by, fmaf(-a.y, bx, a.z)));
    return o;
}

// exact PReLU for any a: a*x + (1-a)*relu(x)  -> mul + max + fma (3 VALU, no vcc)
__device__ __forceinline__ float prelu(const float x, const float a, const float one_m_a) {
    return fmaf(one_m_a, fmaxf(x, 0.0f), a * x);
}

__global__ __launch_bounds__(TPB) void quat_scan_kernel(
    const float* __restrict__ ts,    // (B, CNT)
    const float* __restrict__ gyro,  // (B, CNT, 3)
    const float* __restrict__ sq,    // (B, 4)
    const float* __restrict__ W1, const float* __restrict__ b1, const float* __restrict__ a1p,
    const float* __restrict__ W2, const float* __restrict__ b2, const float* __restrict__ a2p,
    float* __restrict__ out)         // (B, 4)
{
    __shared__ Q s_q[NWAVE];         // 64 B total — no other LDS

    const int  b    = blockIdx.x;
    const int  tid  = threadIdx.x;
    const int  t0   = tid * CHUNK;
    const bool last = (tid == TPB - 1);

    // ---- gyro chunk straight into registers: 7 float4 (28 floats, 112 B/lane,
    // 16B-aligned: 3*t0 floats = 96B*tid). A wave's 7 loads sweep one contiguous
    // 7 KB window -> each line fetched once from HBM, rest are L1/L2 hits.
    float g[28];
    {
        const float4* gp = (const float4*)(gyro + (size_t)b * (CNT * 3) + 3 * t0);
        #pragma unroll
        for (int k = 0; k < 6; ++k) ((float4*)g)[k] = gp[k];
        // 7th float4 (floats 24..27 = step t0+8) would be OOB for tid 255: clamp the
        // ADDRESS (gp+5 is in-bounds). Clamped values only feed the pad step whose
        // scale s is exactly 0 (rt[8]==rt[7]), so any finite data is correct.
        const float4* g6 = gp + (last ? 5 : 6);
        ((float4*)g)[6] = *g6;
    }

    // ---- ts segment into registers (t0 .. t0+8); lane stride 32 B
    float rt[9];
    {
        const float4* tp = (const float4*)(ts + (size_t)b * CNT + t0);
        ((float4*)rt)[0] = tp[0];
        ((float4*)rt)[1] = tp[1];
        const int i8 = last ? (t0 + 7) : (t0 + 8);   // rt[8]==rt[7] -> dt=0 pad step
        rt[8] = ts[(size_t)b * CNT + i8];
    }

    // ---- small params: wave-uniform addresses -> scalar loads -> SGPRs
    float w1[9], w2[9], bb1[3], bb2[3];
    #pragma unroll
    for (int i = 0; i < 9; ++i) { w1[i] = W1[i]; w2[i] = W2[i]; }
    #pragma unroll
    for (int i = 0; i < 3; ++i) { bb1[i] = b1[i]; bb2[i] = b2[i]; }
    const float a1 = a1p[0], a2 = a2p[0];
    const float oma1 = 1.0f - a1, oma2 = 1.0f - a2;

    // g(t) = prelu(W2 @ prelu(W1 @ v + b1, a1) + b2, a2) + v ; register-indexed (const j)
    auto gf = [&](const int j, float& gx, float& gy, float& gz) {
        const float vx = g[3 * j + 0];
        const float vy = g[3 * j + 1];
        const float vz = g[3 * j + 2];
        float h0 = fmaf(w1[0], vx, fmaf(w1[1], vy, fmaf(w1[2], vz, bb1[0])));
        float h1 = fmaf(w1[3], vx, fmaf(w1[4], vy, fmaf(w1[5], vz, bb1[1])));
        float h2 = fmaf(w1[6], vx, fmaf(w1[7], vy, fmaf(w1[8], vz, bb1[2])));
        h0 = prelu(h0, a1, oma1);
        h1 = prelu(h1, a1, oma1);
        h2 = prelu(h2, a1, oma1);
        float u0 = fmaf(w2[0], h0, fmaf(w2[1], h1, fmaf(w2[2], h2, bb2[0])));
        float u1 = fmaf(w2[3], h0, fmaf(w2[4], h1, fmaf(w2[5], h2, bb2[1])));
        float u2 = fmaf(w2[6], h0, fmaf(w2[7], h1, fmaf(w2[8], h2, bb2[2])));
        gx = prelu(u0, a2, oma2) + vx;
        gy = prelu(u1, a2, oma2) + vy;
        gz = prelu(u2, a2, oma2) + vz;
    };

    // ---- ordered chunk product, fully unrolled, branch-free (pad step has dt=0)
    Q q = {1.0f, 0.0f, 0.0f, 0.0f};
    float g0x, g0y, g0z;
    gf(0, g0x, g0y, g0z);
    #pragma unroll
    for (int j = 0; j < CHUNK; ++j) {
        float g1x, g1y, g1z;
        gf(j + 1, g1x, g1y, g1z);
        const float s = 0.25f * (rt[j + 1] - rt[j]);   // gm*dt*0.5 = (g0+g1)*dt*0.25
        q = qmul1(q, (g0x + g1x) * s, (g0y + g1y) * s, (g0z + g1z) * s);
        g0x = g1x; g0y = g1y; g0z = g1z;
    }

    // normalize chunk product (positive rescale keeps reduction bounded; n2 >= 1)
    {
        const float n2  = fmaf(q.w, q.w, fmaf(q.x, q.x, fmaf(q.y, q.y, q.z * q.z)));
        const float inv = 1.0f / sqrtf(n2);
        q.w *= inv; q.x *= inv; q.y *= inv; q.z *= inv;
    }

    // ---- ordered wave-level shuffle reduction (lane 0 gets P_0 ⊗ ... ⊗ P_63)
    #pragma unroll
    for (int sft = 1; sft < 64; sft <<= 1) {
        Q o;
        o.w = __shfl_down(q.w, sft);
        o.x = __shfl_down(q.x, sft);
        o.y = __shfl_down(q.y, sft);
        o.z = __shfl_down(q.z, sft);
        q = qmul(q, o);
    }

    const int lane = tid & 63;
    const int wid  = tid >> 6;
    if (lane == 0) s_q[wid] = q;
    __syncthreads();

    // ---- epilogue: combine wave products in order, apply start quat, normalize
    if (tid == 0) {
        Q acc = s_q[0];
        #pragma unroll
        for (int w = 1; w < NWAVE; ++w) acc = qmul(acc, s_q[w]);

        const float4 s0 = ((const float4*)(sq + (size_t)b * 4))[0];
        const Q q0 = {s0.x, s0.y, s0.z, s0.w};
        Q qf = qmul(q0, acc);
        const float n   = sqrtf(fmaf(qf.w, qf.w, fmaf(qf.x, qf.x, fmaf(qf.y, qf.y, qf.z * qf.z))));
        const float inv = 1.0f / fmaxf(n, 1e-12f);
        float4 o;
        o.x = qf.w * inv; o.y = qf.x * inv; o.z = qf.y * inv; o.w = qf.z * inv;
        ((float4*)(out + (size_t)b * 4))[0] = o;
    }
}

extern "C" void kernel_launch(void* const* d_in, const int* in_sizes, int n_in,
                              void* d_out, int out_size, void* d_ws, size_t ws_size,
                              hipStream_t stream) {
    const float* ts   = (const float*)d_in[0];  // timestampns_set (B, CNT)
    const float* gyro = (const float*)d_in[1];  // gyro_set (B, CNT, 3)
    const float* sq   = (const float*)d_in[2];  // start_quat (B, 4)
    const float* W1   = (const float*)d_in[3];
    const float* b1   = (const float*)d_in[4];
    const float* a1   = (const float*)d_in[5];
    const float* W2   = (const float*)d_in[6];
    const float* b2   = (const float*)d_in[7];
    const float* a2   = (const float*)d_in[8];
    float* out = (float*)d_out;

    const int B = in_sizes[0] / CNT;  // 4096

    quat_scan_kernel<<<B, TPB, 0, stream>>>(ts, gyro, sq, W1, b1, a1, W2, b2, a2, out);
}